// Round 8
// baseline (40.326 us; speedup 1.0000x reference)
//
#include <hip/hip_runtime.h>
#include <math.h>

#define TOPK 8
#define KJ 17
#define BB 512
#define NROWS (BB * KJ)   // 8704
#define DF 3072           // floats per row; 768 float4
#define RPB 4             // rows per block; grid = NROWS/RPB = 2176

// Kernel 1: 4 consecutive rows per block (48KB contiguous). Fewer, longer
// blocks for steadier streaming; 4 independent accumulators give the wave
// more loads in flight. Loss written transposed [KJ][BB] for kernel2.
__global__ __launch_bounds__(256) void row_loss_kernel(
    const float* __restrict__ out,
    const float* __restrict__ tgt,
    const float* __restrict__ w,
    float* __restrict__ loss)   // [KJ][BB]
{
    const int r0 = blockIdx.x * RPB;
    const int tid = threadIdx.x;
    const float4* __restrict__ o4 = (const float4*)(out + (size_t)r0 * DF);
    const float4* __restrict__ t4 = (const float4*)(tgt + (size_t)r0 * DF);

    float acc[RPB];
    #pragma unroll
    for (int j = 0; j < RPB; ++j) {
        float4 a0 = o4[j * 768 + tid];
        float4 a1 = o4[j * 768 + tid + 256];
        float4 a2 = o4[j * 768 + tid + 512];
        float4 b0 = t4[j * 768 + tid];
        float4 b1 = t4[j * 768 + tid + 256];
        float4 b2 = t4[j * 768 + tid + 512];

        float dx = a0.x - b0.x, dy = a0.y - b0.y, dz = a0.z - b0.z, dw = a0.w - b0.w;
        float a = dx * dx + dy * dy + dz * dz + dw * dw;
        dx = a1.x - b1.x; dy = a1.y - b1.y; dz = a1.z - b1.z; dw = a1.w - b1.w;
        a += dx * dx + dy * dy + dz * dz + dw * dw;
        dx = a2.x - b2.x; dy = a2.y - b2.y; dz = a2.z - b2.z; dw = a2.w - b2.w;
        a += dx * dx + dy * dy + dz * dz + dw * dw;
        acc[j] = a;
    }

    const int lane = tid & 63;
    const int wid = tid >> 6;
    __shared__ float part[4][RPB];

    #pragma unroll
    for (int j = 0; j < RPB; ++j) {
        float v = acc[j];
        #pragma unroll
        for (int off = 32; off > 0; off >>= 1)
            v += __shfl_down(v, off, 64);
        if (lane == 0) part[wid][j] = v;
    }
    __syncthreads();

    if (tid < RPB) {
        const int row = r0 + tid;
        float tot = part[0][tid] + part[1][tid] + part[2][tid] + part[3][tid];
        const int b_s = row / KJ;
        const int k_s = row - b_s * KJ;
        loss[k_s * BB + b_s] = tot * w[row];
    }
}

// Kernel 2: single block, one thread per batch element b. Coalesced loads
// from the transposed loss layout.
__global__ __launch_bounds__(512) void topk_mean_kernel(
    const float* __restrict__ loss,   // [KJ][BB]
    float* __restrict__ outp)
{
    const int b = threadIdx.x;
    float per;

    {
        float v[KJ];
        #pragma unroll
        for (int k = 0; k < KJ; ++k)
            v[k] = loss[k * BB + b];

        float sum8 = 0.0f;
        #pragma unroll
        for (int it = 0; it < TOPK; ++it) {
            float m = v[0];
            int mi = 0;
            #pragma unroll
            for (int k = 1; k < KJ; ++k)
                if (v[k] > m) { m = v[k]; mi = k; }
            sum8 += m;
            #pragma unroll
            for (int k = 0; k < KJ; ++k)
                v[k] = (k == mi) ? -INFINITY : v[k];
        }
        per = sum8 * (1.0f / (float)TOPK);
    }

    #pragma unroll
    for (int off = 32; off > 0; off >>= 1)
        per += __shfl_down(per, off, 64);

    __shared__ float s[8];
    const int lane = threadIdx.x & 63;
    const int wid = threadIdx.x >> 6;
    if (lane == 0) s[wid] = per;
    __syncthreads();
    if (threadIdx.x == 0) {
        float tot = 0.0f;
        #pragma unroll
        for (int i = 0; i < 8; ++i) tot += s[i];
        outp[0] = tot / (float)BB;
    }
}

extern "C" void kernel_launch(void* const* d_in, const int* in_sizes, int n_in,
                              void* d_out, int out_size, void* d_ws, size_t ws_size,
                              hipStream_t stream) {
    const float* out_p = (const float*)d_in[0];
    const float* tgt_p = (const float*)d_in[1];
    const float* w_p   = (const float*)d_in[2];
    float* res = (float*)d_out;

    float* loss_ws = (float*)d_ws;  // NROWS floats, [KJ][BB] layout

    row_loss_kernel<<<NROWS / RPB, 256, 0, stream>>>(out_p, tgt_p, w_p, loss_ws);
    topk_mean_kernel<<<1, 512, 0, stream>>>(loss_ws, res);
}